// Round 19
// baseline (108.296 us; speedup 1.0000x reference)
//
#include <hip/hip_runtime.h>

#define B_ 64
#define Q_ 64
#define L_ 8192
#define KCONV 51
#define HC 26
#define HT 251
#define NCH2 34               // conv501 K-chunks of 16 (shift -6)
#define NCH1 6                // conv51  K-chunks of 16 (shift -7)

// ---- workspace layout (bytes), total 69,345,280 <= proven-safe 73.5 MB ----
// PAR floats: a[0..63] @0, scale @64
#define A51_OFF 512           // 6*64*16 = 6144 B
#define TA_OFF  8192          // 64*34*64*16 = 2,228,224 B
#define RN_OFF  2236416       // rn f16 [B][Q][L] = 67,108,864 B

// exact-balance LDS slot permutation (slot = 16B unit), bijective per 8-slot
// group; applied identically on every write and read.
#define MAPB(s) ((((s) & ~7) | ((((s) & 7) + ((s) >> 3)) & 7)) << 4)

typedef _Float16 f16x8 __attribute__((ext_vector_type(8)));
typedef float f32x16 __attribute__((ext_vector_type(16)));
typedef unsigned int uix2 __attribute__((ext_vector_type(2)));

__device__ __forceinline__ float sigm(float v) {
    return 1.0f / (1.0f + __expf(-v));
}

// ---------------- kernel 1: A-tables (Toeplitz fragments) + a/scale ----------------
__global__ __launch_bounds__(256) void k_params(const float* __restrict__ cwh,
                                                const float* __restrict__ tcw,
                                                const float* __restrict__ araw,
                                                float* __restrict__ ws) {
    const int tid = threadIdx.x;
    const int q = blockIdx.x;
    char* wsb = (char*)ws;
    if (q < Q_) {
        // TA[q][c][lane]: A_c[i=lane&31, kappa=8*(lane>>5)+jj] = kt_q[16c+8hi+jj-i-6]
        for (int idx = tid; idx < NCH2 * 64; idx += 256) {
            int c = idx >> 6, lane = idx & 63;
            int hi = lane >> 5, i = lane & 31;
            int mbase = 16 * c + 8 * hi - i - 6;
            f16x8 hv;
            #pragma unroll
            for (int jj = 0; jj < 8; jj++) {
                int m = mbase + jj;
                float v = 0.0f;
                if (m >= 0 && m <= 500) {
                    int hh = (m <= 250) ? m : (500 - m);
                    v = sigm(tcw[q * HT + hh]);
                }
                hv[jj] = (_Float16)v;
            }
            *(f16x8*)(wsb + TA_OFF + ((size_t)q * (NCH2 * 64) + idx) * 16) = hv;
        }
    } else {
        if (tid < Q_) ws[tid] = sigm(araw[tid]);
        // A51[c][lane]: A_c[i,kappa] = kc[16c+8hi+jj-i-7], kc[m]=cwh[min(m,50-m)]
        for (int idx = tid; idx < NCH1 * 64; idx += 256) {
            int c = idx >> 6, lane = idx & 63;
            int hi = lane >> 5, i = lane & 31;
            int mbase = 16 * c + 8 * hi - i - 7;
            f16x8 hv;
            #pragma unroll
            for (int jj = 0; jj < 8; jj++) {
                int m = mbase + jj;
                float v = 0.0f;
                if (m >= 0 && m < KCONV) v = cwh[m < HC ? m : (KCONV - 1 - m)];
                hv[jj] = (_Float16)v;
            }
            *(f16x8*)(wsb + A51_OFF + idx * 16) = hv;
        }
        __syncthreads();
        if (tid == 0) {
            float p = 1.0f;
            for (int j = 0; j < Q_; j++) p *= ws[j];
            float peak = sigm(tcw[(Q_ - 1) * HT + 250]);
            ws[64] = 1.0f / (peak * p);
        }
    }
}

// D-layout -> l-linear LDS write; permlane b128 path (HW-validated r16/r17).
__device__ __forceinline__ void write_dlayout(char* buf, int base_slot,
                                              const float* v, float scale,
                                              int w, int j, int hi) {
    union P4 { _Float16 h[4]; uint2 u; };
    P4 p[4];
    #pragma unroll
    for (int k = 0; k < 4; k++) {
        #pragma unroll
        for (int d = 0; d < 4; d++) p[k].h[d] = (_Float16)(v[4 * k + d] * scale);
    }
#if __has_builtin(__builtin_amdgcn_permlane32_swap)
    uix2 s0x = __builtin_amdgcn_permlane32_swap(p[0].u.x, p[2].u.x, false, false);
    uix2 s0y = __builtin_amdgcn_permlane32_swap(p[0].u.y, p[2].u.y, false, false);
    uix2 s1x = __builtin_amdgcn_permlane32_swap(p[1].u.x, p[3].u.x, false, false);
    uix2 s1y = __builtin_amdgcn_permlane32_swap(p[1].u.y, p[3].u.y, false, false);
    uint4 w0, w1;
    if (hi == 0) {
        w0.x = p[0].u.x; w0.y = p[0].u.y; w0.z = s0x[1]; w0.w = s0y[1];
        w1.x = p[1].u.x; w1.y = p[1].u.y; w1.z = s1x[1]; w1.w = s1y[1];
    } else {
        w0.x = s0x[0]; w0.y = s0y[0]; w0.z = p[2].u.x; w0.w = p[2].u.y;
        w1.x = s1x[0]; w1.y = s1y[0]; w1.z = p[3].u.x; w1.w = p[3].u.y;
    }
    const int s0 = base_slot + 128 * w + 4 * j + 2 * hi;
    *(uint4*)(buf + MAPB(s0)) = w0;
    *(uint4*)(buf + MAPB(s0 + 1)) = w1;
#else
    #pragma unroll
    for (int k = 0; k < 4; k++) {
        const int bo = MAPB(base_slot + 128 * w + 4 * j + k) + 8 * hi;
        *(uint2*)(buf + bo) = p[k].u;
    }
#endif
}

// ---------------- kernel 2: QUAD-row all-MFMA conv51 -> softmax -> conv501 ----------
// block = (q, b-quad); 512 thr = 8 waves; wave w owns l-tile [1024w,1024w+1024)
// for FOUR rows. Each af-load feeds 4 MFMAs; barriers amortized 2x vs pair-row.
// 69.9 KB LDS -> 2 blocks/CU; grid 1024 -> 2 block-rounds/CU.
__global__ __launch_bounds__(512, 4) void k_fused(const float* __restrict__ x,
                                                  float* __restrict__ ws) {
    const int tid = threadIdx.x;
    const int bid = blockIdx.x;
    const int q = bid >> 4, qd = bid & 15;
    char* wsb = (char*)ws;
    __shared__ __attribute__((aligned(128))) char buf[4][17408];  // 1088 slots each
    __shared__ float red[64];           // [r]: mx @ r*16+w, sm @ r*16+8+w

    const int w = tid >> 6, lane = tid & 63, j = lane & 31, hi = lane >> 5;
    int rows[4];
    #pragma unroll
    for (int r = 0; r < 4; r++) rows[r] = (4 * qd + r) * Q_ + q;

    // ---- zero halos (slots 0..31 and 1056..1087, all 4 buffers) ----
    const uint4 z4 = {0u, 0u, 0u, 0u};
    if (tid < 32) {
        #pragma unroll
        for (int r = 0; r < 4; r++) *(uint4*)(buf[r] + MAPB(tid)) = z4;
    } else if (tid >= 64 && tid < 96) {
        int s = 1056 + (tid - 64);
        #pragma unroll
        for (int r = 0; r < 4; r++) *(uint4*)(buf[r] + MAPB(s)) = z4;
    }

    // ---- stage 4 x rows as f16 at halo-256 offset (slots 2t+32, 2t+33) ----
    union H8 { _Float16 h[8]; uint4 u; };
    #pragma unroll
    for (int r = 0; r < 4; r++) {
        const float* xr = x + (size_t)rows[r] * L_ + 16 * tid;
        float4 f0 = *(const float4*)(xr + 0);
        float4 f1 = *(const float4*)(xr + 4);
        float4 f2 = *(const float4*)(xr + 8);
        float4 f3 = *(const float4*)(xr + 12);
        H8 h0, h1;
        h0.h[0] = (_Float16)f0.x; h0.h[1] = (_Float16)f0.y;
        h0.h[2] = (_Float16)f0.z; h0.h[3] = (_Float16)f0.w;
        h0.h[4] = (_Float16)f1.x; h0.h[5] = (_Float16)f1.y;
        h0.h[6] = (_Float16)f1.z; h0.h[7] = (_Float16)f1.w;
        h1.h[0] = (_Float16)f2.x; h1.h[1] = (_Float16)f2.y;
        h1.h[2] = (_Float16)f2.z; h1.h[3] = (_Float16)f2.w;
        h1.h[4] = (_Float16)f3.x; h1.h[5] = (_Float16)f3.y;
        h1.h[6] = (_Float16)f3.z; h1.h[7] = (_Float16)f3.w;
        *(uint4*)(buf[r] + MAPB(2 * tid + 32)) = h0.u;
        *(uint4*)(buf[r] + MAPB(2 * tid + 33)) = h1.u;
    }
    __syncthreads();                                          // S1: x staged

    // ---- conv51 via 6 chunks x 4 rows (each a51 frag feeds 4 MFMAs) ----
    f32x16 acc[4] = {};
    {
        f16x8 p[4][2];
        #pragma unroll
        for (int r = 0; r < 4; r++) {
            p[r][0] = *(const f16x8*)(buf[r] + MAPB(128 * w + 4 * j + 28 + hi));
            p[r][1] = *(const f16x8*)(buf[r] + MAPB(128 * w + 4 * j + 30 + hi));
        }
        #pragma unroll
        for (int c = 0; c < NCH1; c++) {
            f16x8 a51 = *(const f16x8*)(wsb + A51_OFF + (c * 64 + lane) * 16);
            #pragma unroll
            for (int r = 0; r < 4; r++)
                acc[r] = __builtin_amdgcn_mfma_f32_32x32x16_f16(a51, p[r][c & 1], acc[r], 0, 0, 0);
            if (c + 2 < NCH1) {
                const int bo = MAPB(128 * w + 4 * j + 2 * (c + 2) + 28 + hi);
                #pragma unroll
                for (int r = 0; r < 4; r++)
                    p[r][c & 1] = *(const f16x8*)(buf[r] + bo);
            }
        }
    }

    // ---- softmax, 4 rows, ONE barrier (global fixup folded into isum) ----
    float mxr[4], smr[4];
    #pragma unroll
    for (int r = 0; r < 4; r++) {
        float mx = -3.402823466e+38f;
        #pragma unroll
        for (int e = 0; e < 16; e++) mx = fmaxf(mx, acc[r][e]);
        #pragma unroll
        for (int o = 32; o > 0; o >>= 1) mx = fmaxf(mx, __shfl_xor(mx, o));
        float sm = 0.0f;
        #pragma unroll
        for (int e = 0; e < 16; e++) { acc[r][e] = __expf(acc[r][e] - mx); sm += acc[r][e]; }
        #pragma unroll
        for (int o = 32; o > 0; o >>= 1) sm += __shfl_xor(sm, o);
        mxr[r] = mx; smr[r] = sm;
    }
    if (lane == 0) {
        #pragma unroll
        for (int r = 0; r < 4; r++) {
            red[r * 16 + w] = mxr[r];
            red[r * 16 + 8 + w] = smr[r];
        }
    }
    __syncthreads();                                          // S2 (only softmax barrier)
    float isum[4];
    #pragma unroll
    for (int r = 0; r < 4; r++) {
        float mg = red[r * 16];
        #pragma unroll
        for (int i = 1; i < 8; i++) mg = fmaxf(mg, red[r * 16 + i]);
        float ss = 0.0f;
        #pragma unroll
        for (int i = 0; i < 8; i++) ss += red[r * 16 + 8 + i] * __expf(red[r * 16 + i] - mg);
        isum[r] = __expf(mxr[r] - mg) / ss;   // per-wave scale; all lanes have mxr
    }

    // ---- write S (f16) via D-layout transpose (b128 permlane path) ----
    #pragma unroll
    for (int r = 0; r < 4; r++)
        write_dlayout(buf[r], 32, (const float*)&acc[r], isum[r], w, j, hi);
    __syncthreads();                                          // S4: S ready

    // ---- conv501: 34 chunks; each af (L1/L2, dist-4 ring) feeds 4 MFMAs ----
    const char* tab6 = wsb + TA_OFF + ((size_t)q * (NCH2 * 64) + lane) * 16;
    f32x16 o[4] = {};
    {
        f16x8 afr[4], pb[4][2];
        #pragma unroll
        for (int c = 0; c < 4; c++)
            afr[c] = *(const f16x8*)(tab6 + c * 1024);
        #pragma unroll
        for (int r = 0; r < 4; r++) {
            #pragma unroll
            for (int c = 0; c < 2; c++)
                pb[r][c] = *(const f16x8*)(buf[r] + MAPB(128 * w + 4 * j + 2 * c + hi));
        }
        #pragma unroll
        for (int c = 0; c < NCH2; c++) {
            #pragma unroll
            for (int r = 0; r < 4; r++)
                o[r] = __builtin_amdgcn_mfma_f32_32x32x16_f16(afr[c & 3], pb[r][c & 1], o[r], 0, 0, 0);
            if (c + 2 < NCH2) {
                const int bo = MAPB(128 * w + 4 * j + 2 * (c + 2) + hi);
                #pragma unroll
                for (int r = 0; r < 4; r++)
                    pb[r][c & 1] = *(const f16x8*)(buf[r] + bo);
            }
            if (c + 4 < NCH2)
                afr[c & 3] = *(const f16x8*)(tab6 + (c + 4) * 1024);
        }
    }
    __syncthreads();                                          // S5: S reads done

    // ---- transpose outputs to l-linear (slots 0..1023), coalesced rn store ----
    #pragma unroll
    for (int r = 0; r < 4; r++)
        write_dlayout(buf[r], 0, (const float*)&o[r], 1.0f, w, j, hi);
    __syncthreads();                                          // S6
    #pragma unroll
    for (int r = 0; r < 4; r++) {
        uint4 r0 = *(uint4*)(buf[r] + MAPB(2 * tid));
        uint4 r1 = *(uint4*)(buf[r] + MAPB(2 * tid + 1));
        char* dst = wsb + RN_OFF + ((size_t)rows[r] * L_ + 16 * tid) * 2;
        *(uint4*)dst = r0;
        *(uint4*)(dst + 16) = r1;
    }
}

// ---------------- kernel 3: serial-q lattice on rn (exact reference scan) ----------------
__global__ __launch_bounds__(256) void k_lat(const float* __restrict__ ws,
                                             float* __restrict__ out) {
    const int tid = threadIdx.x;
    const int T = blockIdx.x & 7, b = blockIdx.x >> 3;
    const char* wsb = (const char*)ws;
    const int l = 1024 * T + 4 * tid;
    const char* src = wsb + RN_OFF + ((size_t)(b * Q_) * L_ + l) * 2;
    float r[4] = {0.0f, 0.0f, 0.0f, 0.0f};
    float t2[4] = {1.0f, 1.0f, 1.0f, 1.0f};
    union P4 { _Float16 h[4]; uint2 u; };
    P4 cur;
    cur.u = *(const uint2*)src;
    for (int q = 0; q < Q_; q++) {
        P4 nxt = cur;
        if (q < Q_ - 1) nxt.u = *(const uint2*)(src + (size_t)(q + 1) * L_ * 2);
        const float aq = ws[q];
        #pragma unroll
        for (int e = 0; e < 4; e++) {
            float rn = (float)cur.h[e], tn = 1.0f - rn;
            float si = 1.0f / (1.0f - aq * r[e] * rn);
            float rnew = r[e] + aq * rn * t2[e] * si;
            t2[e] = aq * t2[e] * tn * tn * si * si;
            r[e] = rnew;
        }
        cur = nxt;
    }
    const float inv_scale = ws[64];
    float4 o;
    o.x = r[0] * inv_scale; o.y = r[1] * inv_scale;
    o.z = r[2] * inv_scale; o.w = r[3] * inv_scale;
    *(float4*)&out[(size_t)b * L_ + l] = o;
}

extern "C" void kernel_launch(void* const* d_in, const int* in_sizes, int n_in,
                              void* d_out, int out_size, void* d_ws, size_t ws_size,
                              hipStream_t stream) {
    (void)in_sizes; (void)n_in; (void)out_size; (void)ws_size;
    const float* x    = (const float*)d_in[0];
    const float* cwh  = (const float*)d_in[1];
    const float* tcw  = (const float*)d_in[2];
    const float* araw = (const float*)d_in[3];
    float* out = (float*)d_out;
    float* ws  = (float*)d_ws;

    hipLaunchKernelGGL(k_params, dim3(Q_ + 1), dim3(256), 0, stream, cwh, tcw, araw, ws);
    hipLaunchKernelGGL(k_fused, dim3((B_ / 4) * Q_), dim3(512), 0, stream, x, ws);
    hipLaunchKernelGGL(k_lat, dim3(B_ * 8), dim3(256), 0, stream, ws, out);
}

// Round 20
// 96.440 us; speedup vs baseline: 1.1229x; 1.1229x over previous
//
#include <hip/hip_runtime.h>

#define B_ 64
#define Q_ 64
#define L_ 8192
#define KCONV 51
#define HC 26
#define HT 251
#define NCH2 34               // conv501 K-chunks of 16 (shift -6)
#define NCH1 6                // conv51  K-chunks of 16 (shift -7)
#define TAL_CH 34             // ALL conv501 chunks staged in LDS (70.1 KB -> 2 blocks/CU)

// ---- workspace layout (bytes), total 69,345,280 <= proven-safe 73.5 MB ----
// PAR floats: a[0..63] @0, scale @64
#define A51_OFF 512           // 6*64*16 = 6144 B
#define TA_OFF  8192          // 64*34*64*16 = 2,228,224 B
#define RN_OFF  2236416       // rn f16 [B][Q][L] = 67,108,864 B

// exact-balance LDS slot permutation (slot = 16B unit), bijective per 8-slot
// group; applied identically on every write and read.
#define MAPB(s) ((((s) & ~7) | ((((s) & 7) + ((s) >> 3)) & 7)) << 4)

typedef _Float16 f16x8 __attribute__((ext_vector_type(8)));
typedef float f32x16 __attribute__((ext_vector_type(16)));
typedef unsigned int uix2 __attribute__((ext_vector_type(2)));
typedef const __attribute__((address_space(1))) void cg_void;
typedef __attribute__((address_space(3))) void lds_void3;

__device__ __forceinline__ float sigm(float v) {
    return 1.0f / (1.0f + __expf(-v));
}

// ---------------- kernel 1: A-tables (Toeplitz fragments) + a/scale ----------------
__global__ __launch_bounds__(256) void k_params(const float* __restrict__ cwh,
                                                const float* __restrict__ tcw,
                                                const float* __restrict__ araw,
                                                float* __restrict__ ws) {
    const int tid = threadIdx.x;
    const int q = blockIdx.x;
    char* wsb = (char*)ws;
    if (q < Q_) {
        // TA[q][c][lane]: A_c[i=lane&31, kappa=8*(lane>>5)+jj] = kt_q[16c+8hi+jj-i-6]
        for (int idx = tid; idx < NCH2 * 64; idx += 256) {
            int c = idx >> 6, lane = idx & 63;
            int hi = lane >> 5, i = lane & 31;
            int mbase = 16 * c + 8 * hi - i - 6;
            f16x8 hv;
            #pragma unroll
            for (int jj = 0; jj < 8; jj++) {
                int m = mbase + jj;
                float v = 0.0f;
                if (m >= 0 && m <= 500) {
                    int hh = (m <= 250) ? m : (500 - m);
                    v = sigm(tcw[q * HT + hh]);
                }
                hv[jj] = (_Float16)v;
            }
            *(f16x8*)(wsb + TA_OFF + ((size_t)q * (NCH2 * 64) + idx) * 16) = hv;
        }
    } else {
        if (tid < Q_) ws[tid] = sigm(araw[tid]);
        // A51[c][lane]: A_c[i,kappa] = kc[16c+8hi+jj-i-7], kc[m]=cwh[min(m,50-m)]
        for (int idx = tid; idx < NCH1 * 64; idx += 256) {
            int c = idx >> 6, lane = idx & 63;
            int hi = lane >> 5, i = lane & 31;
            int mbase = 16 * c + 8 * hi - i - 7;
            f16x8 hv;
            #pragma unroll
            for (int jj = 0; jj < 8; jj++) {
                int m = mbase + jj;
                float v = 0.0f;
                if (m >= 0 && m < KCONV) v = cwh[m < HC ? m : (KCONV - 1 - m)];
                hv[jj] = (_Float16)v;
            }
            *(f16x8*)(wsb + A51_OFF + idx * 16) = hv;
        }
        __syncthreads();
        if (tid == 0) {
            float p = 1.0f;
            for (int j = 0; j < Q_; j++) p *= ws[j];
            float peak = sigm(tcw[(Q_ - 1) * HT + 250]);
            ws[64] = 1.0f / (peak * p);
        }
    }
}

// D-layout -> l-linear LDS write; permlane b128 path (HW-validated r16/r17).
__device__ __forceinline__ void write_dlayout(char* buf, int base_slot,
                                              const float* v, float scale,
                                              int w, int j, int hi) {
    union P4 { _Float16 h[4]; uint2 u; };
    P4 p[4];
    #pragma unroll
    for (int k = 0; k < 4; k++) {
        #pragma unroll
        for (int d = 0; d < 4; d++) p[k].h[d] = (_Float16)(v[4 * k + d] * scale);
    }
#if __has_builtin(__builtin_amdgcn_permlane32_swap)
    uix2 s0x = __builtin_amdgcn_permlane32_swap(p[0].u.x, p[2].u.x, false, false);
    uix2 s0y = __builtin_amdgcn_permlane32_swap(p[0].u.y, p[2].u.y, false, false);
    uix2 s1x = __builtin_amdgcn_permlane32_swap(p[1].u.x, p[3].u.x, false, false);
    uix2 s1y = __builtin_amdgcn_permlane32_swap(p[1].u.y, p[3].u.y, false, false);
    uint4 w0, w1;
    if (hi == 0) {
        w0.x = p[0].u.x; w0.y = p[0].u.y; w0.z = s0x[1]; w0.w = s0y[1];
        w1.x = p[1].u.x; w1.y = p[1].u.y; w1.z = s1x[1]; w1.w = s1y[1];
    } else {
        w0.x = s0x[0]; w0.y = s0y[0]; w0.z = p[2].u.x; w0.w = p[2].u.y;
        w1.x = s1x[0]; w1.y = s1y[0]; w1.z = p[3].u.x; w1.w = p[3].u.y;
    }
    const int s0 = base_slot + 128 * w + 4 * j + 2 * hi;
    *(uint4*)(buf + MAPB(s0)) = w0;
    *(uint4*)(buf + MAPB(s0 + 1)) = w1;
#else
    #pragma unroll
    for (int k = 0; k < 4; k++) {
        const int bo = MAPB(base_slot + 128 * w + 4 * j + k) + 8 * hi;
        *(uint2*)(buf + bo) = p[k].u;
    }
#endif
}

// ---------------- kernel 2: paired-row all-MFMA conv51 -> softmax -> conv501 ----------
// Best measured structure (r11/r17): TAL staging (now all 34 chunks) + dist-4/dist-2
// rings + 1-barrier softmax + permlane b128 transpose. block = (q, b-pair);
// 512 thr = 8 waves; wave w owns l-tile [1024w,1024w+1024) for BOTH rows.
__global__ __launch_bounds__(512, 4) void k_fused(const float* __restrict__ x,
                                                  float* __restrict__ ws) {
    const int tid = threadIdx.x;
    const int bid = blockIdx.x;
    const int q = bid >> 5, pr = bid & 31;
    const int row0 = (2 * pr) * Q_ + q, row1 = (2 * pr + 1) * Q_ + q;
    char* wsb = (char*)ws;
    __shared__ __attribute__((aligned(128))) char bufA[17408];  // 1088 slots
    __shared__ __attribute__((aligned(128))) char bufB[17408];
    __shared__ __attribute__((aligned(128))) char TAL[TAL_CH * 1024];
    __shared__ float red[32];

    const int w = tid >> 6, lane = tid & 63, j = lane & 31, hi = lane >> 5;

    // ---- issue async TA[q] -> LDS staging first (overlaps x HBM loads) ----
    {
        const char* tabg = wsb + TA_OFF + (size_t)q * (NCH2 * 64) * 16;
        for (int c = w; c < TAL_CH; c += 8) {
            const void* gp = tabg + (c * 64 + lane) * 16;
            __builtin_amdgcn_global_load_lds((cg_void*)gp,
                                             (lds_void3*)(TAL + c * 1024), 16, 0, 0);
        }
    }

    // ---- preload conv51 A-fragments (latency hidden under x loads) ----
    f16x8 a51r[NCH1];
    #pragma unroll
    for (int c = 0; c < NCH1; c++)
        a51r[c] = *(const f16x8*)(wsb + A51_OFF + (c * 64 + lane) * 16);

    // ---- zero halos (slots 0..31 and 1056..1087 of both buffers) ----
    const uint4 z4 = {0u, 0u, 0u, 0u};
    if (tid < 32) {
        *(uint4*)(bufA + MAPB(tid)) = z4;
        *(uint4*)(bufB + MAPB(tid)) = z4;
    } else if (tid >= 64 && tid < 96) {
        int s = 1056 + (tid - 64);
        *(uint4*)(bufA + MAPB(s)) = z4;
        *(uint4*)(bufB + MAPB(s)) = z4;
    }

    // ---- stage both x rows as f16 at halo-256 offset (slots 2t+32, 2t+33) ----
    union H8 { _Float16 h[8]; uint4 u; };
    {
        #pragma unroll
        for (int r = 0; r < 2; r++) {
            const float* xr = x + (size_t)(r ? row1 : row0) * L_ + 16 * tid;
            char* buf = r ? bufB : bufA;
            float4 f0 = *(const float4*)(xr + 0);
            float4 f1 = *(const float4*)(xr + 4);
            float4 f2 = *(const float4*)(xr + 8);
            float4 f3 = *(const float4*)(xr + 12);
            H8 h0, h1;
            h0.h[0] = (_Float16)f0.x; h0.h[1] = (_Float16)f0.y;
            h0.h[2] = (_Float16)f0.z; h0.h[3] = (_Float16)f0.w;
            h0.h[4] = (_Float16)f1.x; h0.h[5] = (_Float16)f1.y;
            h0.h[6] = (_Float16)f1.z; h0.h[7] = (_Float16)f1.w;
            h1.h[0] = (_Float16)f2.x; h1.h[1] = (_Float16)f2.y;
            h1.h[2] = (_Float16)f2.z; h1.h[3] = (_Float16)f2.w;
            h1.h[4] = (_Float16)f3.x; h1.h[5] = (_Float16)f3.y;
            h1.h[6] = (_Float16)f3.z; h1.h[7] = (_Float16)f3.w;
            *(uint4*)(buf + MAPB(2 * tid + 32)) = h0.u;
            *(uint4*)(buf + MAPB(2 * tid + 33)) = h1.u;
        }
    }
    __syncthreads();                                          // S1: x + TAL ready

    // ---- conv51 via 6 MFMAs per row, bf prefetch ring (dist 2) ----
    f32x16 acc0 = {}, acc1 = {};
    {
        f16x8 pA[2], pB[2];
        pA[0] = *(const f16x8*)(bufA + MAPB(128 * w + 4 * j + 28 + hi));
        pB[0] = *(const f16x8*)(bufB + MAPB(128 * w + 4 * j + 28 + hi));
        pA[1] = *(const f16x8*)(bufA + MAPB(128 * w + 4 * j + 30 + hi));
        pB[1] = *(const f16x8*)(bufB + MAPB(128 * w + 4 * j + 30 + hi));
        #pragma unroll
        for (int c = 0; c < NCH1; c++) {
            acc0 = __builtin_amdgcn_mfma_f32_32x32x16_f16(a51r[c], pA[c & 1], acc0, 0, 0, 0);
            acc1 = __builtin_amdgcn_mfma_f32_32x32x16_f16(a51r[c], pB[c & 1], acc1, 0, 0, 0);
            if (c + 2 < NCH1) {
                const int bo = MAPB(128 * w + 4 * j + 2 * (c + 2) + 28 + hi);
                pA[c & 1] = *(const f16x8*)(bufA + bo);
                pB[c & 1] = *(const f16x8*)(bufB + bo);
            }
        }
    }

    // ---- softmax, both rows, ONE barrier (global fixup folded into isum) ----
    float mx0 = -3.402823466e+38f, mx1 = -3.402823466e+38f;
    #pragma unroll
    for (int e = 0; e < 16; e++) { mx0 = fmaxf(mx0, acc0[e]); mx1 = fmaxf(mx1, acc1[e]); }
    #pragma unroll
    for (int o = 32; o > 0; o >>= 1) {
        mx0 = fmaxf(mx0, __shfl_xor(mx0, o));
        mx1 = fmaxf(mx1, __shfl_xor(mx1, o));
    }
    float sm0 = 0.0f, sm1 = 0.0f;
    #pragma unroll
    for (int e = 0; e < 16; e++) {
        acc0[e] = __expf(acc0[e] - mx0); sm0 += acc0[e];
        acc1[e] = __expf(acc1[e] - mx1); sm1 += acc1[e];
    }
    #pragma unroll
    for (int o = 32; o > 0; o >>= 1) { sm0 += __shfl_xor(sm0, o); sm1 += __shfl_xor(sm1, o); }
    if (lane == 0) {
        red[w] = mx0; red[8 + w] = sm0;
        red[16 + w] = mx1; red[24 + w] = sm1;
    }
    __syncthreads();                                          // S2 (only softmax barrier)
    float mg0 = red[0], mg1 = red[16];
    #pragma unroll
    for (int i = 1; i < 8; i++) { mg0 = fmaxf(mg0, red[i]); mg1 = fmaxf(mg1, red[16 + i]); }
    float ss0 = 0.0f, ss1 = 0.0f;
    #pragma unroll
    for (int i = 0; i < 8; i++) {
        ss0 += red[8 + i] * __expf(red[i] - mg0);
        ss1 += red[24 + i] * __expf(red[16 + i] - mg1);
    }
    const float isum0 = __expf(mx0 - mg0) / ss0;   // per-wave scale, all lanes have mx0
    const float isum1 = __expf(mx1 - mg1) / ss1;

    // ---- write S (f16) via D-layout transpose (b128 permlane path) ----
    write_dlayout(bufA, 32, (const float*)&acc0, isum0, w, j, hi);
    write_dlayout(bufB, 32, (const float*)&acc1, isum1, w, j, hi);
    __syncthreads();                                          // S4: S ready

    // ---- conv501: 34 chunks, af ring dist 4 (all from TAL), bf ring dist 2 ----
    f32x16 o0 = {}, o1 = {};
    {
        f16x8 afr[4], pA[2], pB[2];
        #pragma unroll
        for (int c = 0; c < 4; c++)
            afr[c] = *(const f16x8*)(TAL + c * 1024 + lane * 16);
        #pragma unroll
        for (int c = 0; c < 2; c++) {
            const int bo = MAPB(128 * w + 4 * j + 2 * c + hi);
            pA[c] = *(const f16x8*)(bufA + bo);
            pB[c] = *(const f16x8*)(bufB + bo);
        }
        #pragma unroll
        for (int c = 0; c < NCH2; c++) {
            o0 = __builtin_amdgcn_mfma_f32_32x32x16_f16(afr[c & 3], pA[c & 1], o0, 0, 0, 0);
            o1 = __builtin_amdgcn_mfma_f32_32x32x16_f16(afr[c & 3], pB[c & 1], o1, 0, 0, 0);
            if (c + 2 < NCH2) {
                const int bo = MAPB(128 * w + 4 * j + 2 * (c + 2) + hi);
                pA[c & 1] = *(const f16x8*)(bufA + bo);
                pB[c & 1] = *(const f16x8*)(bufB + bo);
            }
            if (c + 4 < NCH2)
                afr[c & 3] = *(const f16x8*)(TAL + (c + 4) * 1024 + lane * 16);
        }
    }
    __syncthreads();                                          // S5: S reads done

    // ---- transpose outputs to l-linear (slots 0..1023, b128 permlane path) ----
    write_dlayout(bufA, 0, (const float*)&o0, 1.0f, w, j, hi);
    write_dlayout(bufB, 0, (const float*)&o1, 1.0f, w, j, hi);
    __syncthreads();                                          // S6
    {
        uint4 r0 = *(uint4*)(bufA + MAPB(2 * tid));
        uint4 r1 = *(uint4*)(bufA + MAPB(2 * tid + 1));
        char* dst = wsb + RN_OFF + ((size_t)row0 * L_ + 16 * tid) * 2;
        *(uint4*)dst = r0;
        *(uint4*)(dst + 16) = r1;
        uint4 r2 = *(uint4*)(bufB + MAPB(2 * tid));
        uint4 r3 = *(uint4*)(bufB + MAPB(2 * tid + 1));
        char* dst1 = wsb + RN_OFF + ((size_t)row1 * L_ + 16 * tid) * 2;
        *(uint4*)dst1 = r2;
        *(uint4*)(dst1 + 16) = r3;
    }
}

// ---------------- kernel 3: serial-q lattice on rn (exact reference scan) ----------------
__global__ __launch_bounds__(256) void k_lat(const float* __restrict__ ws,
                                             float* __restrict__ out) {
    const int tid = threadIdx.x;
    const int T = blockIdx.x & 7, b = blockIdx.x >> 3;
    const char* wsb = (const char*)ws;
    const int l = 1024 * T + 4 * tid;
    const char* src = wsb + RN_OFF + ((size_t)(b * Q_) * L_ + l) * 2;
    float r[4] = {0.0f, 0.0f, 0.0f, 0.0f};
    float t2[4] = {1.0f, 1.0f, 1.0f, 1.0f};
    union P4 { _Float16 h[4]; uint2 u; };
    P4 cur;
    cur.u = *(const uint2*)src;
    for (int q = 0; q < Q_; q++) {
        P4 nxt = cur;
        if (q < Q_ - 1) nxt.u = *(const uint2*)(src + (size_t)(q + 1) * L_ * 2);
        const float aq = ws[q];
        #pragma unroll
        for (int e = 0; e < 4; e++) {
            float rn = (float)cur.h[e], tn = 1.0f - rn;
            float si = 1.0f / (1.0f - aq * r[e] * rn);
            float rnew = r[e] + aq * rn * t2[e] * si;
            t2[e] = aq * t2[e] * tn * tn * si * si;
            r[e] = rnew;
        }
        cur = nxt;
    }
    const float inv_scale = ws[64];
    float4 o;
    o.x = r[0] * inv_scale; o.y = r[1] * inv_scale;
    o.z = r[2] * inv_scale; o.w = r[3] * inv_scale;
    *(float4*)&out[(size_t)b * L_ + l] = o;
}

extern "C" void kernel_launch(void* const* d_in, const int* in_sizes, int n_in,
                              void* d_out, int out_size, void* d_ws, size_t ws_size,
                              hipStream_t stream) {
    (void)in_sizes; (void)n_in; (void)out_size; (void)ws_size;
    const float* x    = (const float*)d_in[0];
    const float* cwh  = (const float*)d_in[1];
    const float* tcw  = (const float*)d_in[2];
    const float* araw = (const float*)d_in[3];
    float* out = (float*)d_out;
    float* ws  = (float*)d_ws;

    hipLaunchKernelGGL(k_params, dim3(Q_ + 1), dim3(256), 0, stream, cwh, tcw, araw, ws);
    hipLaunchKernelGGL(k_fused, dim3((B_ / 2) * Q_), dim3(512), 0, stream, x, ws);
    hipLaunchKernelGGL(k_lat, dim3(B_ * 8), dim3(256), 0, stream, ws, out);
}

// Round 21
// 94.555 us; speedup vs baseline: 1.1453x; 1.0199x over previous
//
#include <hip/hip_runtime.h>

#define B_ 64
#define Q_ 64
#define L_ 8192
#define KCONV 51
#define HC 26
#define HT 251
#define NCH2 34               // conv501 K-chunks of 16 (shift -6)
#define NCH1 6                // conv51  K-chunks of 16 (shift -7)
#define TAL_CH 34             // ALL conv501 chunks staged in LDS

// ---- workspace layout (bytes), total 69,345,280 <= proven-safe 73.5 MB ----
// PAR floats: a[0..63] @0, scale @64
#define A51_OFF 512           // 6*64*16 = 6144 B
#define TA_OFF  8192          // 64*34*64*16 = 2,228,224 B
#define RN_OFF  2236416       // rn f16 [B][Q] x 16384 B/row (PERM layout)

// exact-balance LDS slot permutation (slot = 16B unit), bijective per 8-slot
// group; applied identically on every write and read.
#define MAPB(s) ((((s) & ~7) | ((((s) & 7) + ((s) >> 3)) & 7)) << 4)

typedef _Float16 f16x8 __attribute__((ext_vector_type(8)));
typedef float f32x16 __attribute__((ext_vector_type(16)));
typedef unsigned int uix2 __attribute__((ext_vector_type(2)));
typedef const __attribute__((address_space(1))) void cg_void;
typedef __attribute__((address_space(3))) void lds_void3;

__device__ __forceinline__ float sigm(float v) {
    return 1.0f / (1.0f + __expf(-v));
}

// ---------------- kernel 1: A-tables (Toeplitz fragments) + a/scale ----------------
__global__ __launch_bounds__(256) void k_params(const float* __restrict__ cwh,
                                                const float* __restrict__ tcw,
                                                const float* __restrict__ araw,
                                                float* __restrict__ ws) {
    const int tid = threadIdx.x;
    const int q = blockIdx.x;
    char* wsb = (char*)ws;
    if (q < Q_) {
        // TA[q][c][lane]: A_c[i=lane&31, kappa=8*(lane>>5)+jj] = kt_q[16c+8hi+jj-i-6]
        for (int idx = tid; idx < NCH2 * 64; idx += 256) {
            int c = idx >> 6, lane = idx & 63;
            int hi = lane >> 5, i = lane & 31;
            int mbase = 16 * c + 8 * hi - i - 6;
            f16x8 hv;
            #pragma unroll
            for (int jj = 0; jj < 8; jj++) {
                int m = mbase + jj;
                float v = 0.0f;
                if (m >= 0 && m <= 500) {
                    int hh = (m <= 250) ? m : (500 - m);
                    v = sigm(tcw[q * HT + hh]);
                }
                hv[jj] = (_Float16)v;
            }
            *(f16x8*)(wsb + TA_OFF + ((size_t)q * (NCH2 * 64) + idx) * 16) = hv;
        }
    } else {
        if (tid < Q_) ws[tid] = sigm(araw[tid]);
        // A51[c][lane]: A_c[i,kappa] = kc[16c+8hi+jj-i-7], kc[m]=cwh[min(m,50-m)]
        for (int idx = tid; idx < NCH1 * 64; idx += 256) {
            int c = idx >> 6, lane = idx & 63;
            int hi = lane >> 5, i = lane & 31;
            int mbase = 16 * c + 8 * hi - i - 7;
            f16x8 hv;
            #pragma unroll
            for (int jj = 0; jj < 8; jj++) {
                int m = mbase + jj;
                float v = 0.0f;
                if (m >= 0 && m < KCONV) v = cwh[m < HC ? m : (KCONV - 1 - m)];
                hv[jj] = (_Float16)v;
            }
            *(f16x8*)(wsb + A51_OFF + idx * 16) = hv;
        }
        __syncthreads();
        if (tid == 0) {
            float p = 1.0f;
            for (int j = 0; j < Q_; j++) p *= ws[j];
            float peak = sigm(tcw[(Q_ - 1) * HT + 250]);
            ws[64] = 1.0f / (peak * p);
        }
    }
}

// D-layout -> l-linear LDS write; permlane b128 path (HW-validated r16/r17/r20).
// Used only for the S (softmax) intermediate, which conv501 must read l-linear.
__device__ __forceinline__ void write_dlayout(char* buf, int base_slot,
                                              const float* v, float scale,
                                              int w, int j, int hi) {
    union P4 { _Float16 h[4]; uint2 u; };
    P4 p[4];
    #pragma unroll
    for (int k = 0; k < 4; k++) {
        #pragma unroll
        for (int d = 0; d < 4; d++) p[k].h[d] = (_Float16)(v[4 * k + d] * scale);
    }
#if __has_builtin(__builtin_amdgcn_permlane32_swap)
    uix2 s0x = __builtin_amdgcn_permlane32_swap(p[0].u.x, p[2].u.x, false, false);
    uix2 s0y = __builtin_amdgcn_permlane32_swap(p[0].u.y, p[2].u.y, false, false);
    uix2 s1x = __builtin_amdgcn_permlane32_swap(p[1].u.x, p[3].u.x, false, false);
    uix2 s1y = __builtin_amdgcn_permlane32_swap(p[1].u.y, p[3].u.y, false, false);
    uint4 w0, w1;
    if (hi == 0) {
        w0.x = p[0].u.x; w0.y = p[0].u.y; w0.z = s0x[1]; w0.w = s0y[1];
        w1.x = p[1].u.x; w1.y = p[1].u.y; w1.z = s1x[1]; w1.w = s1y[1];
    } else {
        w0.x = s0x[0]; w0.y = s0y[0]; w0.z = p[2].u.x; w0.w = p[2].u.y;
        w1.x = s1x[0]; w1.y = s1y[0]; w1.z = p[3].u.x; w1.w = p[3].u.y;
    }
    const int s0 = base_slot + 128 * w + 4 * j + 2 * hi;
    *(uint4*)(buf + MAPB(s0)) = w0;
    *(uint4*)(buf + MAPB(s0 + 1)) = w1;
#else
    #pragma unroll
    for (int k = 0; k < 4; k++) {
        const int bo = MAPB(base_slot + 128 * w + 4 * j + k) + 8 * hi;
        *(uint2*)(buf + bo) = p[k].u;
    }
#endif
}

// ---------------- kernel 2: paired-row all-MFMA conv51 -> softmax -> conv501 ----------
// r20 structure (TAL=34, rings, 1-barrier softmax) MINUS the output-transpose LDS
// round-trip: conv501 outputs are stored directly to global in fragment-PERM order
// (lane (w,j,hi) -> row*16384 + w*2048 + (2j+hi)*32 + 8k + 2d; l = 1024w+32j+8k+4hi+d).
// Barriers drop 6 -> 4. block = (q, b-pair); 512 thr = 8 waves.
__global__ __launch_bounds__(512, 4) void k_fused(const float* __restrict__ x,
                                                  float* __restrict__ ws) {
    const int tid = threadIdx.x;
    const int bid = blockIdx.x;
    const int q = bid >> 5, pr = bid & 31;
    const int row0 = (2 * pr) * Q_ + q, row1 = (2 * pr + 1) * Q_ + q;
    char* wsb = (char*)ws;
    __shared__ __attribute__((aligned(128))) char bufA[17408];  // 1088 slots
    __shared__ __attribute__((aligned(128))) char bufB[17408];
    __shared__ __attribute__((aligned(128))) char TAL[TAL_CH * 1024];
    __shared__ float red[32];

    const int w = tid >> 6, lane = tid & 63, j = lane & 31, hi = lane >> 5;

    // ---- issue async TA[q] -> LDS staging first (overlaps x HBM loads) ----
    {
        const char* tabg = wsb + TA_OFF + (size_t)q * (NCH2 * 64) * 16;
        for (int c = w; c < TAL_CH; c += 8) {
            const void* gp = tabg + (c * 64 + lane) * 16;
            __builtin_amdgcn_global_load_lds((cg_void*)gp,
                                             (lds_void3*)(TAL + c * 1024), 16, 0, 0);
        }
    }

    // ---- preload conv51 A-fragments (latency hidden under x loads) ----
    f16x8 a51r[NCH1];
    #pragma unroll
    for (int c = 0; c < NCH1; c++)
        a51r[c] = *(const f16x8*)(wsb + A51_OFF + (c * 64 + lane) * 16);

    // ---- zero halos (slots 0..31 and 1056..1087 of both buffers) ----
    const uint4 z4 = {0u, 0u, 0u, 0u};
    if (tid < 32) {
        *(uint4*)(bufA + MAPB(tid)) = z4;
        *(uint4*)(bufB + MAPB(tid)) = z4;
    } else if (tid >= 64 && tid < 96) {
        int s = 1056 + (tid - 64);
        *(uint4*)(bufA + MAPB(s)) = z4;
        *(uint4*)(bufB + MAPB(s)) = z4;
    }

    // ---- stage both x rows as f16 at halo-256 offset (slots 2t+32, 2t+33) ----
    union H8 { _Float16 h[8]; uint4 u; };
    {
        #pragma unroll
        for (int r = 0; r < 2; r++) {
            const float* xr = x + (size_t)(r ? row1 : row0) * L_ + 16 * tid;
            char* buf = r ? bufB : bufA;
            float4 f0 = *(const float4*)(xr + 0);
            float4 f1 = *(const float4*)(xr + 4);
            float4 f2 = *(const float4*)(xr + 8);
            float4 f3 = *(const float4*)(xr + 12);
            H8 h0, h1;
            h0.h[0] = (_Float16)f0.x; h0.h[1] = (_Float16)f0.y;
            h0.h[2] = (_Float16)f0.z; h0.h[3] = (_Float16)f0.w;
            h0.h[4] = (_Float16)f1.x; h0.h[5] = (_Float16)f1.y;
            h0.h[6] = (_Float16)f1.z; h0.h[7] = (_Float16)f1.w;
            h1.h[0] = (_Float16)f2.x; h1.h[1] = (_Float16)f2.y;
            h1.h[2] = (_Float16)f2.z; h1.h[3] = (_Float16)f2.w;
            h1.h[4] = (_Float16)f3.x; h1.h[5] = (_Float16)f3.y;
            h1.h[6] = (_Float16)f3.z; h1.h[7] = (_Float16)f3.w;
            *(uint4*)(buf + MAPB(2 * tid + 32)) = h0.u;
            *(uint4*)(buf + MAPB(2 * tid + 33)) = h1.u;
        }
    }
    __syncthreads();                                          // S1: x + TAL ready

    // ---- conv51 via 6 MFMAs per row, bf prefetch ring (dist 2) ----
    f32x16 acc0 = {}, acc1 = {};
    {
        f16x8 pA[2], pB[2];
        pA[0] = *(const f16x8*)(bufA + MAPB(128 * w + 4 * j + 28 + hi));
        pB[0] = *(const f16x8*)(bufB + MAPB(128 * w + 4 * j + 28 + hi));
        pA[1] = *(const f16x8*)(bufA + MAPB(128 * w + 4 * j + 30 + hi));
        pB[1] = *(const f16x8*)(bufB + MAPB(128 * w + 4 * j + 30 + hi));
        #pragma unroll
        for (int c = 0; c < NCH1; c++) {
            acc0 = __builtin_amdgcn_mfma_f32_32x32x16_f16(a51r[c], pA[c & 1], acc0, 0, 0, 0);
            acc1 = __builtin_amdgcn_mfma_f32_32x32x16_f16(a51r[c], pB[c & 1], acc1, 0, 0, 0);
            if (c + 2 < NCH1) {
                const int bo = MAPB(128 * w + 4 * j + 2 * (c + 2) + 28 + hi);
                pA[c & 1] = *(const f16x8*)(bufA + bo);
                pB[c & 1] = *(const f16x8*)(bufB + bo);
            }
        }
    }

    // ---- softmax, both rows, ONE barrier (global fixup folded into isum) ----
    float mx0 = -3.402823466e+38f, mx1 = -3.402823466e+38f;
    #pragma unroll
    for (int e = 0; e < 16; e++) { mx0 = fmaxf(mx0, acc0[e]); mx1 = fmaxf(mx1, acc1[e]); }
    #pragma unroll
    for (int o = 32; o > 0; o >>= 1) {
        mx0 = fmaxf(mx0, __shfl_xor(mx0, o));
        mx1 = fmaxf(mx1, __shfl_xor(mx1, o));
    }
    float sm0 = 0.0f, sm1 = 0.0f;
    #pragma unroll
    for (int e = 0; e < 16; e++) {
        acc0[e] = __expf(acc0[e] - mx0); sm0 += acc0[e];
        acc1[e] = __expf(acc1[e] - mx1); sm1 += acc1[e];
    }
    #pragma unroll
    for (int o = 32; o > 0; o >>= 1) { sm0 += __shfl_xor(sm0, o); sm1 += __shfl_xor(sm1, o); }
    if (lane == 0) {
        red[w] = mx0; red[8 + w] = sm0;
        red[16 + w] = mx1; red[24 + w] = sm1;
    }
    __syncthreads();                                          // S2 (only softmax barrier)
    float mg0 = red[0], mg1 = red[16];
    #pragma unroll
    for (int i = 1; i < 8; i++) { mg0 = fmaxf(mg0, red[i]); mg1 = fmaxf(mg1, red[16 + i]); }
    float ss0 = 0.0f, ss1 = 0.0f;
    #pragma unroll
    for (int i = 0; i < 8; i++) {
        ss0 += red[8 + i] * __expf(red[i] - mg0);
        ss1 += red[24 + i] * __expf(red[16 + i] - mg1);
    }
    const float isum0 = __expf(mx0 - mg0) / ss0;   // per-wave scale, all lanes have mx0
    const float isum1 = __expf(mx1 - mg1) / ss1;

    // ---- write S (f16) via D-layout transpose (b128 permlane path) ----
    write_dlayout(bufA, 32, (const float*)&acc0, isum0, w, j, hi);
    write_dlayout(bufB, 32, (const float*)&acc1, isum1, w, j, hi);
    __syncthreads();                                          // S4: S ready

    // ---- conv501: 34 chunks, af ring dist 4 (all from TAL), bf ring dist 2 ----
    f32x16 o0 = {}, o1 = {};
    {
        f16x8 afr[4], pA[2], pB[2];
        #pragma unroll
        for (int c = 0; c < 4; c++)
            afr[c] = *(const f16x8*)(TAL + c * 1024 + lane * 16);
        #pragma unroll
        for (int c = 0; c < 2; c++) {
            const int bo = MAPB(128 * w + 4 * j + 2 * c + hi);
            pA[c] = *(const f16x8*)(bufA + bo);
            pB[c] = *(const f16x8*)(bufB + bo);
        }
        #pragma unroll
        for (int c = 0; c < NCH2; c++) {
            o0 = __builtin_amdgcn_mfma_f32_32x32x16_f16(afr[c & 3], pA[c & 1], o0, 0, 0, 0);
            o1 = __builtin_amdgcn_mfma_f32_32x32x16_f16(afr[c & 3], pB[c & 1], o1, 0, 0, 0);
            if (c + 2 < NCH2) {
                const int bo = MAPB(128 * w + 4 * j + 2 * (c + 2) + hi);
                pA[c & 1] = *(const f16x8*)(bufA + bo);
                pB[c & 1] = *(const f16x8*)(bufB + bo);
            }
            if (c + 4 < NCH2)
                afr[c & 3] = *(const f16x8*)(TAL + (c + 4) * 1024 + lane * 16);
        }
    }

    // ---- direct PERM-layout rn store (no LDS round-trip, no extra barriers) ----
    // lane (w,j,hi): 32 contiguous bytes at row*16384 + w*2048 + (2j+hi)*32;
    // value e=4k+d at +8k+2d  <->  l = 1024w + 32j + 8k + 4hi + d.
    {
        union P4 { _Float16 h[4]; uint2 u; };
        const int lofs = w * 2048 + (2 * j + hi) * 32;
        #pragma unroll
        for (int r = 0; r < 2; r++) {
            const float* v = r ? (const float*)&o1 : (const float*)&o0;
            P4 p[4];
            #pragma unroll
            for (int k = 0; k < 4; k++) {
                #pragma unroll
                for (int d = 0; d < 4; d++) p[k].h[d] = (_Float16)v[4 * k + d];
            }
            uint4 w0, w1;
            w0.x = p[0].u.x; w0.y = p[0].u.y; w0.z = p[1].u.x; w0.w = p[1].u.y;
            w1.x = p[2].u.x; w1.y = p[2].u.y; w1.z = p[3].u.x; w1.w = p[3].u.y;
            char* dst = wsb + RN_OFF + (size_t)(r ? row1 : row0) * 16384 + lofs;
            *(uint4*)dst = w0;
            *(uint4*)(dst + 16) = w1;
        }
    }
}

// ---------------- kernel 3: serial-q lattice on rn (exact reference scan) ----------------
// PERM layout: read address tid*8 + T*2048 is IDENTICAL to the old l-linear address;
// only the out-write index changes (l = 1024T + 32j + 8k + 4hi, j=tid>>3,
// hi=(tid>>2)&1, k=tid&3).
__global__ __launch_bounds__(256) void k_lat(const float* __restrict__ ws,
                                             float* __restrict__ out) {
    const int tid = threadIdx.x;
    const int T = blockIdx.x & 7, b = blockIdx.x >> 3;
    const char* wsb = (const char*)ws;
    const char* src = wsb + RN_OFF + (size_t)(b * Q_) * 16384 + T * 2048 + tid * 8;
    float r[4] = {0.0f, 0.0f, 0.0f, 0.0f};
    float t2[4] = {1.0f, 1.0f, 1.0f, 1.0f};
    union P4 { _Float16 h[4]; uint2 u; };
    P4 cur;
    cur.u = *(const uint2*)src;
    for (int q = 0; q < Q_; q++) {
        P4 nxt = cur;
        if (q < Q_ - 1) nxt.u = *(const uint2*)(src + (size_t)(q + 1) * 16384);
        const float aq = ws[q];
        #pragma unroll
        for (int e = 0; e < 4; e++) {
            float rn = (float)cur.h[e], tn = 1.0f - rn;
            float si = 1.0f / (1.0f - aq * r[e] * rn);
            float rnew = r[e] + aq * rn * t2[e] * si;
            t2[e] = aq * t2[e] * tn * tn * si * si;
            r[e] = rnew;
        }
        cur = nxt;
    }
    const float inv_scale = ws[64];
    const int l = 1024 * T + 32 * (tid >> 3) + 8 * (tid & 3) + 4 * ((tid >> 2) & 1);
    float4 o;
    o.x = r[0] * inv_scale; o.y = r[1] * inv_scale;
    o.z = r[2] * inv_scale; o.w = r[3] * inv_scale;
    *(float4*)&out[(size_t)b * L_ + l] = o;
}

extern "C" void kernel_launch(void* const* d_in, const int* in_sizes, int n_in,
                              void* d_out, int out_size, void* d_ws, size_t ws_size,
                              hipStream_t stream) {
    (void)in_sizes; (void)n_in; (void)out_size; (void)ws_size;
    const float* x    = (const float*)d_in[0];
    const float* cwh  = (const float*)d_in[1];
    const float* tcw  = (const float*)d_in[2];
    const float* araw = (const float*)d_in[3];
    float* out = (float*)d_out;
    float* ws  = (float*)d_ws;

    hipLaunchKernelGGL(k_params, dim3(Q_ + 1), dim3(256), 0, stream, cwh, tcw, araw, ws);
    hipLaunchKernelGGL(k_fused, dim3((B_ / 2) * Q_), dim3(512), 0, stream, x, ws);
    hipLaunchKernelGGL(k_lat, dim3(B_ * 8), dim3(256), 0, stream, ws, out);
}